// Round 5
// baseline (387.881 us; speedup 1.0000x reference)
//
#include <hip/hip_runtime.h>
#include <cstdint>
#include <cstddef>

#define NT 256
#define LOG2E 1.4426950408889634f

typedef float v2f __attribute__((ext_vector_type(2)));
typedef float v4f __attribute__((ext_vector_type(4)));

#if defined(__has_builtin)
#  if __has_builtin(__builtin_amdgcn_exp2f)
#    define EXP2F(x) __builtin_amdgcn_exp2f(x)
#  else
#    define EXP2F(x) exp2f(x)
#  endif
#else
#  define EXP2F(x) exp2f(x)
#endif

// ---------------- shared-memory layout (float offsets) ----------------
enum {
  OFF_EEGB = 0,       // 8
  OFF_PSAW = 8,       // 16
  OFF_PSAB = 24,      // 8
  OFF_LOCW = 32,      // 24
  OFF_LOCB = 56,      // 8
  OFF_TGTW = 64,      // 8
  OFF_TGTB = 72,      // 8
  OFF_NG   = 80,      // 8
  OFF_NB   = 88,      // 8
  OFF_CINW = 96,      // 192 (q-rows pre-scaled by log2e)
  OFF_CINB = 288,     // 24
  OFF_COUTW= 312,     // 64
  OFF_COUTB= 376,     // 8
  OFF_SINW = 384,     // 192
  OFF_SINB = 576,     // 24
  OFF_SOUTW= 600,     // 64
  OFF_SOUTB= 664,     // 8
  OFF_OINW = 672,     // 192
  OFF_OINB = 864,     // 24
  OFF_OOUTW= 888,     // 64
  OFF_OOUTB= 952,     // 8
  OFF_FC1B = 960,     // 90 -> 1050
  OFF_PE30 = 1052,    // 8
  OFF_PE32 = 1060,    // 8 -> 1068
  OFF_Ebuf = 1068,    // 240
  OFF_Pbuf = 1308,    // 256
  OFF_Sbuf = 1564,    // 256
  OFF_Abuf = 1820,    // 256
  OFF_Lbuf = 2076,    // 256
  OFF_Tbuf = 2332,    // 256 (reused as final-MHA raw output for fc1)
  OFF_CAT  = 2588,    // 1008 -> 3596
  OFF_QP   = 3596,    // 16 rows x 20 floats (float2[8] + 4 pad) = 320 -> 3916
  OFF_KS   = 3916,    // 8*68 = 544 (k, h-major, padded stride 68)
  OFF_VS   = 4460,    // 544 -> 5004
  OFF_FCO  = 5004,    // 90 -> 5094
  SM_TOTAL = 5096,    // 20384 B -> 8 blocks/CU
  OFF_EEGW = OFF_KS,  // 672 floats [o][84] padded, aliased: dead before first kv-proj
};

struct MhaDesc { short Lq2, Lk, kstart, qoff, kvoff, wset, dst, flags; };
// flags: 1=project q & zero softmax accum; 2=finalize (out-proj+LN);
//        4=group end (write CAT); 8=save carry (s_cross_l); 16=add carry; 32=zero cat accum

#define EB 0
#define PB 30
#define AB 62
#define SB 94
static __device__ const MhaDesc g_desc[20] = {
  {15, 32, 0, OFF_Ebuf, OFF_Pbuf, 0, EB, 1|2|32},  // cross(e,p)
  {15, 32, 0, OFF_Ebuf, OFF_Abuf, 0, EB, 1|2},     // cross(e,a)
  {15, 32, 0, OFF_Ebuf, OFF_Lbuf, 0, EB, 1|2},     // cross(e,l)
  {15, 30, 0, OFF_Ebuf, OFF_Ebuf, 1, EB, 1|2},     // selfa(e)
  {15, 32, 0, OFF_Ebuf, OFF_Sbuf, 0, EB, 1|2|4},   // cross(e,s)
  {16, 30, 0, OFF_Pbuf, OFF_Ebuf, 0, PB, 1|2|32},  // cross(p,e)
  {16, 32, 0, OFF_Pbuf, OFF_Abuf, 0, PB, 1|2},     // cross(p,a)
  {16, 32, 0, OFF_Pbuf, OFF_Lbuf, 0, PB, 1|2},     // cross(p,l)
  {16, 32, 0, OFF_Pbuf, OFF_Pbuf, 1, PB, 1|2},     // selfa(p)
  {16, 32, 0, OFF_Pbuf, OFF_Sbuf, 0, PB, 1|2|4},   // cross(p,s)
  {16, 30, 0, OFF_Sbuf, OFF_Ebuf, 0, SB, 1|2|32},  // cross(s,e)
  {16, 32, 0, OFF_Sbuf, OFF_Pbuf, 0, SB, 1|2},     // cross(s,p)
  {16, 32, 0, OFF_Sbuf, OFF_Abuf, 0, SB, 1|2},     // cross(s,a)
  {16, 32, 0, OFF_Sbuf, OFF_Lbuf, 0, SB, 1|2|4|8}, // cross(s,l) -> S, carry to A
  {16, 30, 0, OFF_Abuf, OFF_Ebuf, 0, AB, 1|2|32},  // cross(a,e)
  {16, 32, 0, OFF_Abuf, OFF_Pbuf, 0, AB, 1|2},     // cross(a,p)
  {16, 32, 0, OFF_Abuf, OFF_Abuf, 1, AB, 1|2},     // selfa(a)
  {16, 32, 0, OFF_Abuf, OFF_Sbuf, 0, AB, 1|2|4|16},// cross(a,s) + carried s_cross_l
  {16, 64, 0,  OFF_Tbuf, OFF_CAT, 2, -1, 1},       // final MHA pass 1 (k 0..63)
  {16, 62, 64, OFF_Tbuf, OFF_CAT, 2, -1, 2},       // final MHA pass 2 (k 64..125)
};

__device__ __forceinline__ float grp8_sum(float v) {
  v += __shfl_xor(v, 1);
  v += __shfl_xor(v, 2);
  v += __shfl_xor(v, 4);
  return v;
}

__device__ __forceinline__ float dot8(const float* __restrict__ x,
                                      const float* __restrict__ w, float bias) {
  v4f xa = *(const v4f*)x, xb = *(const v4f*)(x + 4);
  v4f p = xa * *(const v4f*)w;
  p += xb * *(const v4f*)(w + 4);
  v2f q = p.xy + p.zw;
  return bias + q.x + q.y;
}

// fully-unrolled 2-q-row attention accumulation: K/V read ONCE for both rows
template<int LK>
__device__ __forceinline__ void attn2(float q1, float q2,
                                      const float* __restrict__ Kp,
                                      const float* __restrict__ Vp,
                                      v4f& la, v4f& Aa, v4f& lb, v4f& Ab) {
  #pragma unroll
  for (int t = 0; t < (LK >> 2); t++) {
    v4f kk = *(const v4f*)(Kp + 4 * t);
    v4f vv = *(const v4f*)(Vp + 4 * t);
    v4f s1 = kk * q1, s2 = kk * q2;
    v4f e1 = { EXP2F(s1.x), EXP2F(s1.y), EXP2F(s1.z), EXP2F(s1.w) };
    v4f e2 = { EXP2F(s2.x), EXP2F(s2.y), EXP2F(s2.z), EXP2F(s2.w) };
    la += e1; Aa += e1 * vv;
    lb += e2; Ab += e2 * vv;
  }
  if constexpr ((LK & 3) != 0) {  // tail == 2 in all shapes used
    v2f kk = *(const v2f*)(Kp + (LK & ~3));
    v2f vv = *(const v2f*)(Vp + (LK & ~3));
    v2f s1 = kk * q1, s2 = kk * q2;
    v2f e1 = { EXP2F(s1.x), EXP2F(s1.y) };
    v2f e2 = { EXP2F(s2.x), EXP2F(s2.y) };
    la.xy = la.xy + e1; Aa.xy = Aa.xy + e1 * vv;
    lb.xy = lb.xy + e2; Ab.xy = Ab.xy + e2 * vv;
  }
}

__global__ __launch_bounds__(NT, 8) void cmt_kernel(
    const float* __restrict__ eeg, const float* __restrict__ pupil,
    const float* __restrict__ speech, const float* __restrict__ action,
    const float* __restrict__ location, const float* __restrict__ tgt,
    const float* __restrict__ eeg_w, const float* __restrict__ eeg_b,
    const float* __restrict__ psa_w, const float* __restrict__ psa_b,
    const float* __restrict__ loc_w, const float* __restrict__ loc_b,
    const float* __restrict__ tgt_w, const float* __restrict__ tgt_b,
    const float* __restrict__ ng, const float* __restrict__ nb,
    const float* __restrict__ cin_w, const float* __restrict__ cin_b,
    const float* __restrict__ cout_w, const float* __restrict__ cout_b,
    const float* __restrict__ sin_w, const float* __restrict__ sin_b,
    const float* __restrict__ sout_w, const float* __restrict__ sout_b,
    const float* __restrict__ oin_w, const float* __restrict__ oin_b,
    const float* __restrict__ oout_w, const float* __restrict__ oout_b,
    const float* __restrict__ fc1_w, const float* __restrict__ fc1_b,
    float* __restrict__ out)
{
  __shared__ __align__(16) float sm[SM_TOTAL];
  const int tid = threadIdx.x;
  const int b = blockIdx.x;

#define CP(off, p, n) for (int i = tid; i < (n); i += NT) sm[(off)+i] = (p)[i]
#define CPQ(off, p, n, nq) for (int i = tid; i < (n); i += NT) sm[(off)+i] = (p)[i] * ((i < (nq)) ? LOG2E : 1.0f)

  // ---------- phase 0: stage weights ----------
  // eeg weights [o][80] -> padded [o][84] rows (aliased into dead K/V scratch)
  for (int i = tid; i < 640; i += NT) sm[OFF_EEGW + (i / 80) * 84 + (i % 80)] = eeg_w[i];
  CP(OFF_EEGB, eeg_b, 8);
  CP(OFF_PSAW, psa_w, 16);   CP(OFF_PSAB, psa_b, 8);
  CP(OFF_LOCW, loc_w, 24);   CP(OFF_LOCB, loc_b, 8);
  CP(OFF_TGTW, tgt_w, 8);    CP(OFF_TGTB, tgt_b, 8);
  CP(OFF_NG, ng, 8);         CP(OFF_NB, nb, 8);
  CPQ(OFF_CINW, cin_w, 192, 64);  CPQ(OFF_CINB, cin_b, 24, 8);
  CP(OFF_COUTW, cout_w, 64); CP(OFF_COUTB, cout_b, 8);
  CPQ(OFF_SINW, sin_w, 192, 64);  CPQ(OFF_SINB, sin_b, 24, 8);
  CP(OFF_SOUTW, sout_w, 64); CP(OFF_SOUTB, sout_b, 8);
  CPQ(OFF_OINW, oin_w, 192, 64);  CPQ(OFF_OINB, oin_b, 24, 8);
  CP(OFF_OOUTW, oout_w, 64); CP(OFF_OOUTB, oout_b, 8);
  CP(OFF_FC1B, fc1_b, 90);
  if (tid < 16) {
    const float divs[4] = {1.f, 0.1f, 0.01f, 0.001f};
    float pos = (tid < 8) ? 30.f : 32.f;
    int e = tid & 7;
    float x = pos * divs[e >> 1];
    float v = (e & 1) ? cosf(x) : sinf(x);
    sm[((tid < 8) ? OFF_PE30 : OFF_PE32) + e] = v;
  }
  __syncthreads();

  // ---------- phase 1: convs + positional encoding ----------
  if (tid < 240) {  // eeg conv2d -> e[30][8]; weights as 20x b128, packed fma
    int w = tid >> 3, o = tid & 7;
    const float* ep = eeg + (size_t)b * 4720 + 4 * w;
    const float* wr = sm + OFF_EEGW + o * 84;
    v4f acc4 = {0.f, 0.f, 0.f, 0.f};
    #pragma unroll
    for (int t = 0; t < 20; t++) {
      int ik0 = 2 * t, ik1 = 2 * t + 1;
      float2 x0 = *(const float2*)(ep + (ik0 / 20) * 2360 + (ik0 % 20) * 118);
      float2 x1 = *(const float2*)(ep + (ik1 / 20) * 2360 + (ik1 % 20) * 118);
      v4f xv = {x0.x, x0.y, x1.x, x1.y};
      acc4 += xv * *(const v4f*)(wr + 4 * t);
    }
    v2f s2 = acc4.xy + acc4.zw;
    sm[OFF_Ebuf + w * 8 + o] = s2.x + s2.y + sm[OFF_EEGB + o] + sm[OFF_PE30 + o];
  }
  {  // conv1d k=1 pad=1 -> length-32 sequences, + pe32
    int t = tid >> 3, o = tid & 7;
    bool inb = (t >= 1 && t <= 30);
    int ti = t - 1;
    float pe = sm[OFF_PE32 + o];
    float w0 = sm[OFF_PSAW + 2 * o], w1 = sm[OFF_PSAW + 2 * o + 1];
    float pb = sm[OFF_PSAB + o];
    float vp = pb, vs = pb, va = pb;
    float vl = sm[OFF_LOCB + o], vt = sm[OFF_TGTB + o];
    if (inb) {
      const float* pp = pupil    + (size_t)b * 60 + ti;
      const float* sp = speech   + (size_t)b * 60 + ti;
      const float* ap = action   + (size_t)b * 60 + ti;
      const float* lp = location + (size_t)b * 90 + ti;
      vp = fmaf(pp[0], w0, fmaf(pp[30], w1, vp));
      vs = fmaf(sp[0], w0, fmaf(sp[30], w1, vs));
      va = fmaf(ap[0], w0, fmaf(ap[30], w1, va));
      vl = fmaf(lp[0],  sm[OFF_LOCW + 3 * o],     vl);
      vl = fmaf(lp[30], sm[OFF_LOCW + 3 * o + 1], vl);
      vl = fmaf(lp[60], sm[OFF_LOCW + 3 * o + 2], vl);
      vt = fmaf(tgt[(size_t)b * 30 + ti], sm[OFF_TGTW + o], vt);
    }
    sm[OFF_Pbuf + tid] = vp + pe;
    sm[OFF_Sbuf + tid] = vs + pe;
    sm[OFF_Abuf + tid] = va + pe;
    sm[OFF_Lbuf + tid] = vl + pe;
    sm[OFF_Tbuf + tid] = vt + pe;
  }
  __syncthreads();

  // ---------- phase 2: 19 MHAs, 2 q-rows per thread, register CAT ----------
  const int qi = tid >> 3, h = tid & 7;
  float q1 = 0.f, q2 = 0.f;
  float cat1 = 0.f, cat2 = 0.f, car1 = 0.f, car2 = 0.f;
  v4f la = {0.f,0.f,0.f,0.f}, Aa = la, lb = la, Ab = la;
  float2* const qp2 = (float2*)(sm + OFF_QP);

  for (int mi = 0; mi < 20; mi++) {
    const MhaDesc d = g_desc[mi];
    int winO, binO, woutO, boutO;
    if (d.wset == 0)      { winO = OFF_CINW; binO = OFF_CINB; woutO = OFF_COUTW; boutO = OFF_COUTB; }
    else if (d.wset == 1) { winO = OFF_SINW; binO = OFF_SINB; woutO = OFF_SOUTW; boutO = OFF_SOUTB; }
    else                  { winO = OFF_OINW; binO = OFF_OINB; woutO = OFF_OOUTW; boutO = OFF_OOUTB; }
    const int nact = d.Lq2 * 8;

    if (d.flags & 32) { cat1 = 0.f; cat2 = 0.f; }

    // q projection for both rows (shared weights; pre-scaled by log2e)
    if ((d.flags & 1) && tid < nact) {
      const float* w = sm + winO + h * 8;
      float bq = sm[binO + h];
      q1 = dot8(sm + d.qoff + qi * 8, w, bq);
      q2 = dot8(sm + d.qoff + (qi + d.Lq2) * 8, w, bq);
      la = (v4f){0.f,0.f,0.f,0.f}; Aa = la; lb = la; Ab = la;
    }
    // k,v projection: 128 threads, weights hoisted to registers, 2-4 rows each
    if (tid < 128) {
      const float* wk = sm + winO + 64 + h * 8;
      const float* wv = sm + winO + 128 + h * 8;
      v4f ka = *(const v4f*)wk, kb = *(const v4f*)(wk + 4);
      v4f va = *(const v4f*)wv, vb = *(const v4f*)(wv + 4);
      float bk = sm[binO + 8 + h], bv = sm[binO + 16 + h];
      for (int idx = tid; idx < d.Lk * 8; idx += 128) {
        int r = idx >> 3;  // h invariant: 128 % 8 == 0
        const float* x = sm + d.kvoff + (d.kstart + r) * 8;
        v4f xa = *(const v4f*)x, xb = *(const v4f*)(x + 4);
        v4f pk = xa * ka; pk += xb * kb;
        v4f pv = xa * va; pv += xb * vb;
        v2f hk = pk.xy + pk.zw, hv = pv.xy + pv.zw;
        sm[OFF_KS + h * 68 + r] = bk + hk.x + hk.y;
        sm[OFF_VS + h * 68 + r] = bv + hv.x + hv.y;
      }
    }
    __syncthreads();

    // attention: K/V read once for 2 q rows (no max pass: shift-invariant, bounded)
    if (tid < nact) {
      const float* Kp = sm + OFF_KS + h * 68;
      const float* Vp = sm + OFF_VS + h * 68;
      switch (d.Lk) {
        case 32: attn2<32>(q1, q2, Kp, Vp, la, Aa, lb, Ab); break;
        case 30: attn2<30>(q1, q2, Kp, Vp, la, Aa, lb, Ab); break;
        case 64: attn2<64>(q1, q2, Kp, Vp, la, Aa, lb, Ab); break;
        case 62: attn2<62>(q1, q2, Kp, Vp, la, Aa, lb, Ab); break;
        default: __builtin_unreachable();
      }
      if (d.flags & 2) {
        v2f lp1 = la.xy + la.zw, ap1 = Aa.xy + Aa.zw;
        v2f lp2 = lb.xy + lb.zw, ap2 = Ab.xy + Ab.zw;
        float ov1 = (ap1.x + ap1.y) * __builtin_amdgcn_rcpf(lp1.x + lp1.y);
        float ov2 = (ap2.x + ap2.y) * __builtin_amdgcn_rcpf(lp2.x + lp2.y);
        // intra-8-lane-group exchange (same wave, no barrier): padded row stride 20
        qp2[qi * 10 + h] = make_float2(ov1, ov2);
        const v4f* row = (const v4f*)(sm + OFF_QP + qi * 20);
        v4f c0 = row[0], c1 = row[1], c2 = row[2], c3 = row[3];
        const float* wo = sm + woutO + h * 8;
        v4f wa = *(const v4f*)wo, wb = *(const v4f*)(wo + 4);
        float bo = sm[boutO + h];
        float a1 = bo, a2 = bo;
        a1 = fmaf(c0.x, wa.x, a1); a2 = fmaf(c0.y, wa.x, a2);
        a1 = fmaf(c0.z, wa.y, a1); a2 = fmaf(c0.w, wa.y, a2);
        a1 = fmaf(c1.x, wa.z, a1); a2 = fmaf(c1.y, wa.z, a2);
        a1 = fmaf(c1.z, wa.w, a1); a2 = fmaf(c1.w, wa.w, a2);
        a1 = fmaf(c2.x, wb.x, a1); a2 = fmaf(c2.y, wb.x, a2);
        a1 = fmaf(c2.z, wb.y, a1); a2 = fmaf(c2.w, wb.y, a2);
        a1 = fmaf(c3.x, wb.z, a1); a2 = fmaf(c3.y, wb.z, a2);
        a1 = fmaf(c3.z, wb.w, a1); a2 = fmaf(c3.w, wb.w, a2);
        if (d.dst >= 0) {
          float gg = sm[OFF_NG + h], bb = sm[OFF_NB + h];
          float mu1 = grp8_sum(a1) * 0.125f;
          float dd1 = a1 - mu1;
          float nv1 = fmaf(dd1 * rsqrtf(grp8_sum(dd1 * dd1) * 0.125f + 1e-5f), gg, bb);
          float mu2 = grp8_sum(a2) * 0.125f;
          float dd2 = a2 - mu2;
          float nv2 = fmaf(dd2 * rsqrtf(grp8_sum(dd2 * dd2) * 0.125f + 1e-5f), gg, bb);
          if (d.flags & 8) { car1 = nv1; car2 = nv2; }
          cat1 += nv1; cat2 += nv2;
          if (d.flags & 16) { cat1 += car1; cat2 += car2; }
          if (d.flags & 4) {
            sm[OFF_CAT + (d.dst + qi) * 8 + h] = cat1;
            sm[OFF_CAT + (d.dst + qi + d.Lq2) * 8 + h] = cat2;
          }
        } else {
          // final MHA raw output (32,8) -> Tbuf (dead) for fc1
          sm[OFF_Tbuf + qi * 8 + h] = a1;
          sm[OFF_Tbuf + (qi + 16) * 8 + h] = a2;
        }
      }
    }
    __syncthreads();
  }

  // ---------- phase 3: fc1 (2 threads per output) + channel softmax ----------
  if (tid < 180) {
    int j = tid >> 1, p = tid & 1;
    const v4f* w4 = (const v4f*)(fc1_w + j * 256);
    const v4f* o4 = (const v4f*)(sm + OFF_Tbuf);
    v4f acc4 = {0.f, 0.f, 0.f, 0.f};
    #pragma unroll 8
    for (int c = p; c < 64; c += 2) acc4 += o4[c] * w4[c];
    v2f a2 = acc4.xy + acc4.zw;
    float acc = a2.x + a2.y;
    acc += __shfl_xor(acc, 1);
    if (p == 0) sm[OFF_FCO + j] = acc + sm[OFF_FC1B + j];
  }
  __syncthreads();
  if (tid < 30) {
    float x0 = sm[OFF_FCO + 3 * tid], x1 = sm[OFF_FCO + 3 * tid + 1], x2 = sm[OFF_FCO + 3 * tid + 2];
    float m = fmaxf(x0, fmaxf(x1, x2));
    float e0 = __expf(x0 - m), e1 = __expf(x1 - m), e2 = __expf(x2 - m);
    float inv = __builtin_amdgcn_rcpf(e0 + e1 + e2);
    float* op = out + (size_t)b * 90;
    op[tid]      = e0 * inv;
    op[30 + tid] = e1 * inv;
    op[60 + tid] = e2 * inv;
  }
#undef CP
#undef CPQ
}

extern "C" void kernel_launch(void* const* d_in, const int* in_sizes, int n_in,
                              void* d_out, int out_size, void* d_ws, size_t ws_size,
                              hipStream_t stream) {
  (void)n_in; (void)out_size; (void)d_ws; (void)ws_size;
  int B = in_sizes[0] / 4720;  // eeg = (B,2,20,118)
  cmt_kernel<<<B, NT, 0, stream>>>(
      (const float*)d_in[0],  (const float*)d_in[1],  (const float*)d_in[2],
      (const float*)d_in[3],  (const float*)d_in[4],  (const float*)d_in[5],
      (const float*)d_in[6],  (const float*)d_in[7],  (const float*)d_in[8],
      (const float*)d_in[9],  (const float*)d_in[10], (const float*)d_in[11],
      (const float*)d_in[12], (const float*)d_in[13], (const float*)d_in[14],
      (const float*)d_in[15], (const float*)d_in[16], (const float*)d_in[17],
      (const float*)d_in[18], (const float*)d_in[19], (const float*)d_in[20],
      (const float*)d_in[21], (const float*)d_in[22], (const float*)d_in[23],
      (const float*)d_in[24], (const float*)d_in[25], (const float*)d_in[26],
      (const float*)d_in[27], (const float*)d_in[28], (const float*)d_in[29],
      (float*)d_out);
}

// Round 6
// 314.770 us; speedup vs baseline: 1.2323x; 1.2323x over previous
//
#include <hip/hip_runtime.h>
#include <cstdint>
#include <cstddef>

#define NT 256
#define LOG2E 1.4426950408889634f

typedef float v2f __attribute__((ext_vector_type(2)));
typedef float v4f __attribute__((ext_vector_type(4)));

#if defined(__has_builtin)
#  if __has_builtin(__builtin_amdgcn_exp2f)
#    define EXP2F(x) __builtin_amdgcn_exp2f(x)
#  else
#    define EXP2F(x) exp2f(x)
#  endif
#else
#  define EXP2F(x) exp2f(x)
#endif

// ---------------- shared-memory layout (float offsets) ----------------
enum {
  OFF_EEGB = 0,       // 8
  OFF_PSAW = 8,       // 16
  OFF_PSAB = 24,      // 8
  OFF_LOCW = 32,      // 24
  OFF_LOCB = 56,      // 8
  OFF_TGTW = 64,      // 8
  OFF_TGTB = 72,      // 8
  OFF_NG   = 80,      // 8
  OFF_NB   = 88,      // 8
  OFF_CINW = 96,      // 192 (q-rows pre-scaled by log2e)
  OFF_CINB = 288,     // 24
  OFF_COUTW= 312,     // 64
  OFF_COUTB= 376,     // 8
  OFF_SINW = 384,     // 192
  OFF_SINB = 576,     // 24
  OFF_SOUTW= 600,     // 64
  OFF_SOUTB= 664,     // 8
  OFF_OINW = 672,     // 192
  OFF_OINB = 864,     // 24
  OFF_OOUTW= 888,     // 64
  OFF_OOUTB= 952,     // 8
  OFF_FC1B = 960,     // 90 -> 1050
  OFF_PE30 = 1052,    // 8
  OFF_PE32 = 1060,    // 8 -> 1068
  OFF_Ebuf = 1068,    // 240
  OFF_Pbuf = 1308,    // 256
  OFF_Sbuf = 1564,    // 256
  OFF_Abuf = 1820,    // 256
  OFF_Lbuf = 2076,    // 256
  OFF_Tbuf = 2332,    // 256 (final-MHA q source; later raw output for fc1)
  OFF_CAT  = 2588,    // 1008 -> 3596
  OFF_QP   = 3596,    // 16 groups x 20 (row1 ov[8], row2 ov[8], 4 pad) -> 3916
  OFF_KS   = 3916,    // 8*68 = 544 (k, h-major, padded stride 68)
  OFF_VS   = 4460,    // 544 -> 5004
  OFF_FCO  = 5004,    // 90 -> 5094
  SM_TOTAL = 5096,    // 20384 B -> 8 blocks/CU
  OFF_EEGW = OFF_KS,  // 672 floats [o][84] padded, aliased: dead before first kv-proj
};

struct MhaDesc { short Lq2, Lk, kstart, qoff, kvoff, wset, dst1, dst2, flags; };
// flags bit0: first pass (project q); bit1: finalize (out-proj + LN / store)

#define EB 0
#define PB 30
#define AB 62
#define SB 94
static __device__ const MhaDesc g_desc[20] = {
  {15, 32, 0, OFF_Ebuf, OFF_Pbuf, 0, EB, -1, 3},   // cross(e,p)
  {15, 32, 0, OFF_Ebuf, OFF_Abuf, 0, EB, -1, 3},   // cross(e,a)
  {15, 32, 0, OFF_Ebuf, OFF_Lbuf, 0, EB, -1, 3},   // cross(e,l)
  {15, 30, 0, OFF_Ebuf, OFF_Ebuf, 1, EB, -1, 3},   // selfa(e)
  {15, 32, 0, OFF_Ebuf, OFF_Sbuf, 0, EB, -1, 3},   // cross(e,s)
  {16, 30, 0, OFF_Pbuf, OFF_Ebuf, 0, PB, -1, 3},   // cross(p,e)
  {16, 32, 0, OFF_Pbuf, OFF_Abuf, 0, PB, -1, 3},   // cross(p,a)
  {16, 32, 0, OFF_Pbuf, OFF_Lbuf, 0, PB, -1, 3},   // cross(p,l)
  {16, 32, 0, OFF_Pbuf, OFF_Pbuf, 1, PB, -1, 3},   // selfa(p)
  {16, 32, 0, OFF_Pbuf, OFF_Sbuf, 0, PB, -1, 3},   // cross(p,s)
  {16, 30, 0, OFF_Sbuf, OFF_Ebuf, 0, SB, -1, 3},   // cross(s,e)
  {16, 32, 0, OFF_Sbuf, OFF_Pbuf, 0, SB, -1, 3},   // cross(s,p)
  {16, 32, 0, OFF_Sbuf, OFF_Abuf, 0, SB, -1, 3},   // cross(s,a)
  {16, 32, 0, OFF_Sbuf, OFF_Lbuf, 0, SB, AB, 3},   // cross(s,l) -> speech AND action
  {16, 30, 0, OFF_Abuf, OFF_Ebuf, 0, AB, -1, 3},   // cross(a,e)
  {16, 32, 0, OFF_Abuf, OFF_Pbuf, 0, AB, -1, 3},   // cross(a,p)
  {16, 32, 0, OFF_Abuf, OFF_Abuf, 1, AB, -1, 3},   // selfa(a)
  {16, 32, 0, OFF_Abuf, OFF_Sbuf, 0, AB, -1, 3},   // cross(a,s)
  {16, 64, 0,  OFF_Tbuf, OFF_CAT, 2, -1, -1, 1},   // final MHA pass 1 (k 0..63)
  {16, 62, 64, OFF_Tbuf, OFF_CAT, 2, -1, -1, 2},   // final MHA pass 2 (k 64..125)
};

__device__ __forceinline__ float grp8_sum(float v) {
  v += __shfl_xor(v, 1);
  v += __shfl_xor(v, 2);
  v += __shfl_xor(v, 4);
  return v;
}

__device__ __forceinline__ float dot8(const float* __restrict__ x,
                                      const float* __restrict__ w, float bias) {
  v4f xa = *(const v4f*)x, xb = *(const v4f*)(x + 4);
  v4f p = xa * *(const v4f*)w;
  p += xb * *(const v4f*)(w + 4);
  v2f q = p.xy + p.zw;
  return bias + q.x + q.y;
}

// fully-unrolled 2-q-row attention: K/V read ONCE for both rows
template<int LK>
__device__ __forceinline__ void attn2(float q1, float q2,
                                      const float* __restrict__ Kp,
                                      const float* __restrict__ Vp,
                                      v4f& la, v4f& Aa, v4f& lb, v4f& Ab) {
  #pragma unroll
  for (int t = 0; t < (LK >> 2); t++) {
    v4f kk = *(const v4f*)(Kp + 4 * t);
    v4f vv = *(const v4f*)(Vp + 4 * t);
    v4f s1 = kk * q1, s2 = kk * q2;
    v4f e1 = { EXP2F(s1.x), EXP2F(s1.y), EXP2F(s1.z), EXP2F(s1.w) };
    v4f e2 = { EXP2F(s2.x), EXP2F(s2.y), EXP2F(s2.z), EXP2F(s2.w) };
    la += e1; Aa += e1 * vv;
    lb += e2; Ab += e2 * vv;
  }
  if constexpr ((LK & 3) != 0) {  // tail == 2 in all shapes used
    v2f kk = *(const v2f*)(Kp + (LK & ~3));
    v2f vv = *(const v2f*)(Vp + (LK & ~3));
    v2f s1 = kk * q1, s2 = kk * q2;
    v2f e1 = { EXP2F(s1.x), EXP2F(s1.y) };
    v2f e2 = { EXP2F(s2.x), EXP2F(s2.y) };
    la.xy = la.xy + e1; Aa.xy = Aa.xy + e1 * vv;
    lb.xy = lb.xy + e2; Ab.xy = Ab.xy + e2 * vv;
  }
}

__global__ __launch_bounds__(NT, 8) void cmt_kernel(
    const float* __restrict__ eeg, const float* __restrict__ pupil,
    const float* __restrict__ speech, const float* __restrict__ action,
    const float* __restrict__ location, const float* __restrict__ tgt,
    const float* __restrict__ eeg_w, const float* __restrict__ eeg_b,
    const float* __restrict__ psa_w, const float* __restrict__ psa_b,
    const float* __restrict__ loc_w, const float* __restrict__ loc_b,
    const float* __restrict__ tgt_w, const float* __restrict__ tgt_b,
    const float* __restrict__ ng, const float* __restrict__ nb,
    const float* __restrict__ cin_w, const float* __restrict__ cin_b,
    const float* __restrict__ cout_w, const float* __restrict__ cout_b,
    const float* __restrict__ sin_w, const float* __restrict__ sin_b,
    const float* __restrict__ sout_w, const float* __restrict__ sout_b,
    const float* __restrict__ oin_w, const float* __restrict__ oin_b,
    const float* __restrict__ oout_w, const float* __restrict__ oout_b,
    const float* __restrict__ fc1_w, const float* __restrict__ fc1_b,
    float* __restrict__ out)
{
  __shared__ __align__(16) float sm[SM_TOTAL];
  const int tid = threadIdx.x;
  const int b = blockIdx.x;

#define CP(off, p, n) for (int i = tid; i < (n); i += NT) sm[(off)+i] = (p)[i]
#define CPQ(off, p, n, nq) for (int i = tid; i < (n); i += NT) sm[(off)+i] = (p)[i] * ((i < (nq)) ? LOG2E : 1.0f)

  // ---------- phase 0: stage weights ----------
  // eeg weights [o][80] -> padded [o][84] rows (aliased into dead K/V scratch)
  for (int i = tid; i < 640; i += NT) sm[OFF_EEGW + (i / 80) * 84 + (i % 80)] = eeg_w[i];
  CP(OFF_EEGB, eeg_b, 8);
  CP(OFF_PSAW, psa_w, 16);   CP(OFF_PSAB, psa_b, 8);
  CP(OFF_LOCW, loc_w, 24);   CP(OFF_LOCB, loc_b, 8);
  CP(OFF_TGTW, tgt_w, 8);    CP(OFF_TGTB, tgt_b, 8);
  CP(OFF_NG, ng, 8);         CP(OFF_NB, nb, 8);
  CPQ(OFF_CINW, cin_w, 192, 64);  CPQ(OFF_CINB, cin_b, 24, 8);
  CP(OFF_COUTW, cout_w, 64); CP(OFF_COUTB, cout_b, 8);
  CPQ(OFF_SINW, sin_w, 192, 64);  CPQ(OFF_SINB, sin_b, 24, 8);
  CP(OFF_SOUTW, sout_w, 64); CP(OFF_SOUTB, sout_b, 8);
  CPQ(OFF_OINW, oin_w, 192, 64);  CPQ(OFF_OINB, oin_b, 24, 8);
  CP(OFF_OOUTW, oout_w, 64); CP(OFF_OOUTB, oout_b, 8);
  CP(OFF_FC1B, fc1_b, 90);
  for (int i = tid; i < 1008; i += NT) sm[OFF_CAT + i] = 0.f;
  if (tid < 16) {
    const float divs[4] = {1.f, 0.1f, 0.01f, 0.001f};
    float pos = (tid < 8) ? 30.f : 32.f;
    int e = tid & 7;
    float x = pos * divs[e >> 1];
    float v = (e & 1) ? cosf(x) : sinf(x);
    sm[((tid < 8) ? OFF_PE30 : OFF_PE32) + e] = v;
  }
  __syncthreads();

  // ---------- phase 1: convs + positional encoding ----------
  if (tid < 240) {  // eeg conv2d -> e[30][8]; weights as 20x b128, packed fma
    int w = tid >> 3, o = tid & 7;
    const float* ep = eeg + (size_t)b * 4720 + 4 * w;
    const float* wr = sm + OFF_EEGW + o * 84;
    v4f acc4 = {0.f, 0.f, 0.f, 0.f};
    #pragma unroll
    for (int t = 0; t < 20; t++) {
      int ik0 = 2 * t, ik1 = 2 * t + 1;
      float2 x0 = *(const float2*)(ep + (ik0 / 20) * 2360 + (ik0 % 20) * 118);
      float2 x1 = *(const float2*)(ep + (ik1 / 20) * 2360 + (ik1 % 20) * 118);
      v4f xv = {x0.x, x0.y, x1.x, x1.y};
      acc4 += xv * *(const v4f*)(wr + 4 * t);
    }
    v2f s2 = acc4.xy + acc4.zw;
    sm[OFF_Ebuf + w * 8 + o] = s2.x + s2.y + sm[OFF_EEGB + o] + sm[OFF_PE30 + o];
  }
  {  // conv1d k=1 pad=1 -> length-32 sequences, + pe32
    int t = tid >> 3, o = tid & 7;
    bool inb = (t >= 1 && t <= 30);
    int ti = t - 1;
    float pe = sm[OFF_PE32 + o];
    float w0 = sm[OFF_PSAW + 2 * o], w1 = sm[OFF_PSAW + 2 * o + 1];
    float pb = sm[OFF_PSAB + o];
    float vp = pb, vs = pb, va = pb;
    float vl = sm[OFF_LOCB + o], vt = sm[OFF_TGTB + o];
    if (inb) {
      const float* pp = pupil    + (size_t)b * 60 + ti;
      const float* sp = speech   + (size_t)b * 60 + ti;
      const float* ap = action   + (size_t)b * 60 + ti;
      const float* lp = location + (size_t)b * 90 + ti;
      vp = fmaf(pp[0], w0, fmaf(pp[30], w1, vp));
      vs = fmaf(sp[0], w0, fmaf(sp[30], w1, vs));
      va = fmaf(ap[0], w0, fmaf(ap[30], w1, va));
      vl = fmaf(lp[0],  sm[OFF_LOCW + 3 * o],     vl);
      vl = fmaf(lp[30], sm[OFF_LOCW + 3 * o + 1], vl);
      vl = fmaf(lp[60], sm[OFF_LOCW + 3 * o + 2], vl);
      vt = fmaf(tgt[(size_t)b * 30 + ti], sm[OFF_TGTW + o], vt);
    }
    sm[OFF_Pbuf + tid] = vp + pe;
    sm[OFF_Sbuf + tid] = vs + pe;
    sm[OFF_Abuf + tid] = va + pe;
    sm[OFF_Lbuf + tid] = vl + pe;
    sm[OFF_Tbuf + tid] = vt + pe;
  }
  __syncthreads();

  // ---------- phase 2: 19 MHAs, 2 q-rows per thread ----------
  const int qi = tid >> 3, h = tid & 7;
  // ONLY persistent state across barriers: q1,q2 + folded final-MHA carry (6 VGPRs)
  float q1 = 0.f, q2 = 0.f, fl1 = 0.f, fa1 = 0.f, fl2 = 0.f, fa2 = 0.f;

  for (int mi = 0; mi < 20; mi++) {
    const MhaDesc d = g_desc[mi];
    int winO, binO, woutO, boutO;
    if (d.wset == 0)      { winO = OFF_CINW; binO = OFF_CINB; woutO = OFF_COUTW; boutO = OFF_COUTB; }
    else if (d.wset == 1) { winO = OFF_SINW; binO = OFF_SINB; woutO = OFF_SOUTW; boutO = OFF_SOUTB; }
    else                  { winO = OFF_OINW; binO = OFF_OINB; woutO = OFF_OOUTW; boutO = OFF_OOUTB; }
    const int nact = d.Lq2 * 8;

    // q projection for both rows (weights pre-scaled by log2e)
    if ((d.flags & 1) && tid < nact) {
      const float* w = sm + winO + h * 8;
      float bq = sm[binO + h];
      q1 = dot8(sm + d.qoff + qi * 8, w, bq);
      q2 = dot8(sm + d.qoff + (qi + d.Lq2) * 8, w, bq);
    }
    // k,v projection into h-major padded arrays (256 threads, <=2 rows each)
    for (int idx = tid; idx < d.Lk * 8; idx += NT) {
      int r = idx >> 3, hh = idx & 7;
      const float* x = sm + d.kvoff + (d.kstart + r) * 8;
      v4f xa = *(const v4f*)x, xb = *(const v4f*)(x + 4);
      const float* wk = sm + winO + 64 + hh * 8;
      const float* wv = sm + winO + 128 + hh * 8;
      v4f pk = xa * *(const v4f*)wk;  pk += xb * *(const v4f*)(wk + 4);
      v4f pv = xa * *(const v4f*)wv;  pv += xb * *(const v4f*)(wv + 4);
      v2f hk = pk.xy + pk.zw, hv = pv.xy + pv.zw;
      sm[OFF_KS + hh * 68 + r] = sm[binO + 8 + hh]  + hk.x + hk.y;
      sm[OFF_VS + hh * 68 + r] = sm[binO + 16 + hh] + hv.x + hv.y;
    }
    __syncthreads();

    // attention: K/V read once for 2 q rows (no max pass: shift-invariant, bounded)
    if (tid < nact) {
      v4f la = {0.f,0.f,0.f,0.f}, Aa = la, lb = la, Ab = la;  // block-scoped: dead at barrier
      const float* Kp = sm + OFF_KS + h * 68;
      const float* Vp = sm + OFF_VS + h * 68;
      switch (d.Lk) {
        case 32: attn2<32>(q1, q2, Kp, Vp, la, Aa, lb, Ab); break;
        case 30: attn2<30>(q1, q2, Kp, Vp, la, Aa, lb, Ab); break;
        case 64: attn2<64>(q1, q2, Kp, Vp, la, Aa, lb, Ab); break;
        case 62: attn2<62>(q1, q2, Kp, Vp, la, Aa, lb, Ab); break;
        default: __builtin_unreachable();
      }
      // fold to scalars immediately
      v2f t1 = la.xy + la.zw, u1 = Aa.xy + Aa.zw;
      v2f t2 = lb.xy + lb.zw, u2 = Ab.xy + Ab.zw;
      float l1 = t1.x + t1.y, s1 = u1.x + u1.y;
      float l2 = t2.x + t2.y, s2 = u2.x + u2.y;
      if (!(d.flags & 2)) {
        fl1 = l1; fa1 = s1; fl2 = l2; fa2 = s2;   // final-MHA pass 1: stash carry
      } else {
        if (!(d.flags & 1)) { l1 += fl1; s1 += fa1; l2 += fl2; s2 += fa2; }  // pass 2: merge
        float ov1 = s1 * __builtin_amdgcn_rcpf(l1);
        float ov2 = s2 * __builtin_amdgcn_rcpf(l2);
        // intra-8-lane-group exchange (same wave, program order -> no barrier)
        sm[OFF_QP + qi * 20 + h]     = ov1;
        sm[OFF_QP + qi * 20 + 8 + h] = ov2;
        const float* wo = sm + woutO + h * 8;
        float bo = sm[boutO + h];
        // row 1, then row 2 (sequential: low register pressure)
        float a1 = dot8(sm + OFF_QP + qi * 20,     wo, bo);
        float a2 = dot8(sm + OFF_QP + qi * 20 + 8, wo, bo);
        if (d.dst1 >= 0) {
          float gg = sm[OFF_NG + h], bb = sm[OFF_NB + h];
          float mu1 = grp8_sum(a1) * 0.125f;
          float dd1 = a1 - mu1;
          float nv1 = fmaf(dd1 * rsqrtf(grp8_sum(dd1 * dd1) * 0.125f + 1e-5f), gg, bb);
          float mu2 = grp8_sum(a2) * 0.125f;
          float dd2 = a2 - mu2;
          float nv2 = fmaf(dd2 * rsqrtf(grp8_sum(dd2 * dd2) * 0.125f + 1e-5f), gg, bb);
          sm[OFF_CAT + (d.dst1 + qi) * 8 + h]          += nv1;
          sm[OFF_CAT + (d.dst1 + qi + d.Lq2) * 8 + h]  += nv2;
          if (d.dst2 >= 0) {
            sm[OFF_CAT + (d.dst2 + qi) * 8 + h]         += nv1;
            sm[OFF_CAT + (d.dst2 + qi + d.Lq2) * 8 + h] += nv2;
          }
        } else {
          sm[OFF_Tbuf + qi * 8 + h]        = a1;  // final raw output (32,8) for fc1
          sm[OFF_Tbuf + (qi + 16) * 8 + h] = a2;
        }
      }
    }
    __syncthreads();
  }

  // ---------- phase 3: fc1 (2 threads per output) + channel softmax ----------
  if (tid < 180) {
    int j = tid >> 1, p = tid & 1;
    const v4f* w4 = (const v4f*)(fc1_w + j * 256);
    const v4f* o4 = (const v4f*)(sm + OFF_Tbuf);
    v4f acc4 = {0.f, 0.f, 0.f, 0.f};
    #pragma unroll 8
    for (int c = p; c < 64; c += 2) acc4 += o4[c] * w4[c];
    v2f a2 = acc4.xy + acc4.zw;
    float acc = a2.x + a2.y;
    acc += __shfl_xor(acc, 1);
    if (p == 0) sm[OFF_FCO + j] = acc + sm[OFF_FC1B + j];
  }
  __syncthreads();
  if (tid < 30) {
    float x0 = sm[OFF_FCO + 3 * tid], x1 = sm[OFF_FCO + 3 * tid + 1], x2 = sm[OFF_FCO + 3 * tid + 2];
    float m = fmaxf(x0, fmaxf(x1, x2));
    float e0 = __expf(x0 - m), e1 = __expf(x1 - m), e2 = __expf(x2 - m);
    float inv = __builtin_amdgcn_rcpf(e0 + e1 + e2);
    float* op = out + (size_t)b * 90;
    op[tid]      = e0 * inv;
    op[30 + tid] = e1 * inv;
    op[60 + tid] = e2 * inv;
  }
#undef CP
#undef CPQ
}

extern "C" void kernel_launch(void* const* d_in, const int* in_sizes, int n_in,
                              void* d_out, int out_size, void* d_ws, size_t ws_size,
                              hipStream_t stream) {
  (void)n_in; (void)out_size; (void)d_ws; (void)ws_size;
  int B = in_sizes[0] / 4720;  // eeg = (B,2,20,118)
  cmt_kernel<<<B, NT, 0, stream>>>(
      (const float*)d_in[0],  (const float*)d_in[1],  (const float*)d_in[2],
      (const float*)d_in[3],  (const float*)d_in[4],  (const float*)d_in[5],
      (const float*)d_in[6],  (const float*)d_in[7],  (const float*)d_in[8],
      (const float*)d_in[9],  (const float*)d_in[10], (const float*)d_in[11],
      (const float*)d_in[12], (const float*)d_in[13], (const float*)d_in[14],
      (const float*)d_in[15], (const float*)d_in[16], (const float*)d_in[17],
      (const float*)d_in[18], (const float*)d_in[19], (const float*)d_in[20],
      (const float*)d_in[21], (const float*)d_in[22], (const float*)d_in[23],
      (const float*)d_in[24], (const float*)d_in[25], (const float*)d_in[26],
      (const float*)d_in[27], (const float*)d_in[28], (const float*)d_in[29],
      (float*)d_out);
}

// Round 8
// 251.033 us; speedup vs baseline: 1.5451x; 1.2539x over previous
//
#include <hip/hip_runtime.h>
#include <cstdint>
#include <cstddef>

#define NT 256
#define LOG2E 1.4426950408889634f

typedef float v2f __attribute__((ext_vector_type(2)));
typedef float v4f __attribute__((ext_vector_type(4)));

#if defined(__has_builtin)
#  if __has_builtin(__builtin_amdgcn_exp2f)
#    define EXP2F(x) __builtin_amdgcn_exp2f(x)
#  else
#    define EXP2F(x) exp2f(x)
#  endif
#else
#  define EXP2F(x) exp2f(x)
#endif

// ---------------- shared-memory layout (float offsets) ----------------
enum {
  OFF_EEGB = 0,       // 8
  OFF_PSAW = 8,       // 16
  OFF_PSAB = 24,      // 8
  OFF_LOCW = 32,      // 24
  OFF_LOCB = 56,      // 8
  OFF_TGTW = 64,      // 8
  OFF_TGTB = 72,      // 8
  OFF_NG   = 80,      // 8
  OFF_NB   = 88,      // 8
  OFF_CINW = 96,      // 192 (q-rows pre-scaled by log2e)
  OFF_CINB = 288,     // 24
  OFF_COUTW= 312,     // 64
  OFF_COUTB= 376,     // 8
  OFF_SINW = 384,     // 192
  OFF_SINB = 576,     // 24
  OFF_SOUTW= 600,     // 64
  OFF_SOUTB= 664,     // 8
  OFF_OINW = 672,     // 192
  OFF_OINB = 864,     // 24
  OFF_OOUTW= 888,     // 64
  OFF_OOUTB= 952,     // 8
  OFF_FC1B = 960,     // 90 -> 1050
  OFF_PE30 = 1052,    // 8
  OFF_PE32 = 1060,    // 8 -> 1068
  OFF_Ebuf = 1068,    // 240
  OFF_Pbuf = 1308,    // 256
  OFF_Sbuf = 1564,    // 256
  OFF_Abuf = 1820,    // 256
  OFF_Lbuf = 2076,    // 256
  OFF_Tbuf = 2332,    // 256 (final q source; then final raw output for fc1)
  OFF_CAT  = 2588,    // 1008 -> 3596 (written exactly once per cell, no init)
  OFF_QP   = 3596,    // 32 groups x 20 = 640 -> 4236  (R7 BUG FIX: was 16 groups, qi<=31 overflowed into K8)
  OFF_K8   = 4236,    // 8 sets x 8h x 36 = 2304 -> 6540
  OFF_V8   = 6540,    // 2304 -> 8844
  OFF_FCO  = 8844,    // 90 -> 8934
  SM_TOTAL = 8936,    // 35744 B -> 4 blocks/CU, 16 waves
  // aliases into K8/V8 region (time-disjoint):
  OFF_EEGW = OFF_K8,            // 672 floats [o][84], dead before phase A
  OFF_KF   = OFF_K8,            // final MHA K: 8h x 132 = 1056
  OFF_VF   = OFF_K8 + 1056,     // final MHA V: 1056 (ends 6348 <= 6540)
};

// KV set ids: 0=e,1=p,2=s,3=a,4=l (cross-proj), 5=e,6=p,7=a (self-proj)

__device__ __forceinline__ float grp8_sum(float v) {
  v += __shfl_xor(v, 1);
  v += __shfl_xor(v, 2);
  v += __shfl_xor(v, 4);
  return v;
}

__device__ __forceinline__ float dot8(const float* __restrict__ x,
                                      const float* __restrict__ w, float bias) {
  v4f xa = *(const v4f*)x, xb = *(const v4f*)(x + 4);
  v4f p = xa * *(const v4f*)w;
  p += xb * *(const v4f*)(w + 4);
  v2f q = p.xy + p.zw;
  return bias + q.x + q.y;
}

// one K/V projection pass for a set (1 row,h item per thread)
template<int LK>
__device__ __forceinline__ void kvproj(int set, int src, int winO, int binO,
                                       float* __restrict__ sm, int tid) {
  if (tid < LK * 8) {
    int r = tid >> 3, hh = tid & 7;
    const float* x = sm + src + r * 8;
    float kk = dot8(x, sm + winO + 64 + hh * 8, sm[binO + 8 + hh]);
    float vv = dot8(x, sm + winO + 128 + hh * 8, sm[binO + 16 + hh]);
    sm[OFF_K8 + set * 288 + hh * 36 + r] = kk;
    sm[OFF_V8 + set * 288 + hh * 36 + r] = vv;
  }
}

// full attention for one (qi,h): softmax (no max pass; shift-invariant, bounded),
// out-projection via intra-wave LDS exchange, LayerNorm. Returns nv.
template<int LK>
__device__ __forceinline__ float attn_nv(float q, int qi, int h, int set,
                                         int woutO, int boutO, float* __restrict__ sm) {
  const float* Kp = sm + OFF_K8 + set * 288 + h * 36;
  const float* Vp = sm + OFF_V8 + set * 288 + h * 36;
  v4f l4 = {0.f,0.f,0.f,0.f}, A4 = {0.f,0.f,0.f,0.f};
  #pragma unroll
  for (int t = 0; t < (LK >> 2); t++) {
    v4f kk = *(const v4f*)(Kp + 4 * t);
    v4f vv = *(const v4f*)(Vp + 4 * t);
    v4f sc = kk * q;
    v4f ee = { EXP2F(sc.x), EXP2F(sc.y), EXP2F(sc.z), EXP2F(sc.w) };
    l4 += ee; A4 += ee * vv;
  }
  if constexpr ((LK & 3) != 0) {  // tail == 2
    v2f kk = *(const v2f*)(Kp + (LK & ~3));
    v2f vv = *(const v2f*)(Vp + (LK & ~3));
    v2f sc = kk * q;
    v2f ee = { EXP2F(sc.x), EXP2F(sc.y) };
    l4.xy = l4.xy + ee; A4.xy = A4.xy + ee * vv;
  }
  v2f lp = l4.xy + l4.zw, ap = A4.xy + A4.zw;
  float ov = (ap.x + ap.y) * __builtin_amdgcn_rcpf(lp.x + lp.y);
  sm[OFF_QP + qi * 20 + h] = ov;          // same-wave exchange (program order)
  float a = dot8(sm + OFF_QP + qi * 20, sm + woutO + h * 8, sm[boutO + h]);
  float mu = grp8_sum(a) * 0.125f;
  float dd = a - mu;
  return fmaf(dd * rsqrtf(grp8_sum(dd * dd) * 0.125f + 1e-5f),
              sm[OFF_NG + h], sm[OFF_NB + h]);
}

__global__ __launch_bounds__(NT, 4) void cmt_kernel(
    const float* __restrict__ eeg, const float* __restrict__ pupil,
    const float* __restrict__ speech, const float* __restrict__ action,
    const float* __restrict__ location, const float* __restrict__ tgt,
    const float* __restrict__ eeg_w, const float* __restrict__ eeg_b,
    const float* __restrict__ psa_w, const float* __restrict__ psa_b,
    const float* __restrict__ loc_w, const float* __restrict__ loc_b,
    const float* __restrict__ tgt_w, const float* __restrict__ tgt_b,
    const float* __restrict__ ng, const float* __restrict__ nb,
    const float* __restrict__ cin_w, const float* __restrict__ cin_b,
    const float* __restrict__ cout_w, const float* __restrict__ cout_b,
    const float* __restrict__ sin_w, const float* __restrict__ sin_b,
    const float* __restrict__ sout_w, const float* __restrict__ sout_b,
    const float* __restrict__ oin_w, const float* __restrict__ oin_b,
    const float* __restrict__ oout_w, const float* __restrict__ oout_b,
    const float* __restrict__ fc1_w, const float* __restrict__ fc1_b,
    float* __restrict__ out)
{
  __shared__ __align__(16) float sm[SM_TOTAL];
  const int tid = threadIdx.x;
  const int b = blockIdx.x;

#define CP(off, p, n) for (int i = tid; i < (n); i += NT) sm[(off)+i] = (p)[i]
#define CPQ(off, p, n, nq) for (int i = tid; i < (n); i += NT) sm[(off)+i] = (p)[i] * ((i < (nq)) ? LOG2E : 1.0f)

  // ---------- phase 0: stage weights ----------
  for (int i = tid; i < 640; i += NT) sm[OFF_EEGW + (i / 80) * 84 + (i % 80)] = eeg_w[i];
  CP(OFF_EEGB, eeg_b, 8);
  CP(OFF_PSAW, psa_w, 16);   CP(OFF_PSAB, psa_b, 8);
  CP(OFF_LOCW, loc_w, 24);   CP(OFF_LOCB, loc_b, 8);
  CP(OFF_TGTW, tgt_w, 8);    CP(OFF_TGTB, tgt_b, 8);
  CP(OFF_NG, ng, 8);         CP(OFF_NB, nb, 8);
  CPQ(OFF_CINW, cin_w, 192, 64);  CPQ(OFF_CINB, cin_b, 24, 8);
  CP(OFF_COUTW, cout_w, 64); CP(OFF_COUTB, cout_b, 8);
  CPQ(OFF_SINW, sin_w, 192, 64);  CPQ(OFF_SINB, sin_b, 24, 8);
  CP(OFF_SOUTW, sout_w, 64); CP(OFF_SOUTB, sout_b, 8);
  CPQ(OFF_OINW, oin_w, 192, 64);  CPQ(OFF_OINB, oin_b, 24, 8);
  CP(OFF_OOUTW, oout_w, 64); CP(OFF_OOUTB, oout_b, 8);
  CP(OFF_FC1B, fc1_b, 90);
  if (tid < 16) {
    const float divs[4] = {1.f, 0.1f, 0.01f, 0.001f};
    float pos = (tid < 8) ? 30.f : 32.f;
    int e = tid & 7;
    float x = pos * divs[e >> 1];
    float v = (e & 1) ? cosf(x) : sinf(x);
    sm[((tid < 8) ? OFF_PE30 : OFF_PE32) + e] = v;
  }
  __syncthreads();

  // ---------- phase 1: convs + positional encoding ----------
  if (tid < 240) {  // eeg conv2d -> e[30][8]
    int w = tid >> 3, o = tid & 7;
    const float* ep = eeg + (size_t)b * 4720 + 4 * w;
    const float* wr = sm + OFF_EEGW + o * 84;
    v4f acc4 = {0.f, 0.f, 0.f, 0.f};
    #pragma unroll
    for (int t = 0; t < 20; t++) {
      int ik0 = 2 * t, ik1 = 2 * t + 1;
      float2 x0 = *(const float2*)(ep + (ik0 / 20) * 2360 + (ik0 % 20) * 118);
      float2 x1 = *(const float2*)(ep + (ik1 / 20) * 2360 + (ik1 % 20) * 118);
      v4f xv = {x0.x, x0.y, x1.x, x1.y};
      acc4 += xv * *(const v4f*)(wr + 4 * t);
    }
    v2f s2 = acc4.xy + acc4.zw;
    sm[OFF_Ebuf + w * 8 + o] = s2.x + s2.y + sm[OFF_EEGB + o] + sm[OFF_PE30 + o];
  }
  {  // conv1d k=1 pad=1 -> length-32 sequences, + pe32
    int t = tid >> 3, o = tid & 7;
    bool inb = (t >= 1 && t <= 30);
    int ti = t - 1;
    float pe = sm[OFF_PE32 + o];
    float w0 = sm[OFF_PSAW + 2 * o], w1 = sm[OFF_PSAW + 2 * o + 1];
    float pb = sm[OFF_PSAB + o];
    float vp = pb, vs = pb, va = pb;
    float vl = sm[OFF_LOCB + o], vt = sm[OFF_TGTB + o];
    if (inb) {
      const float* pp = pupil    + (size_t)b * 60 + ti;
      const float* sp = speech   + (size_t)b * 60 + ti;
      const float* ap = action   + (size_t)b * 60 + ti;
      const float* lp = location + (size_t)b * 90 + ti;
      vp = fmaf(pp[0], w0, fmaf(pp[30], w1, vp));
      vs = fmaf(sp[0], w0, fmaf(sp[30], w1, vs));
      va = fmaf(ap[0], w0, fmaf(ap[30], w1, va));
      vl = fmaf(lp[0],  sm[OFF_LOCW + 3 * o],     vl);
      vl = fmaf(lp[30], sm[OFF_LOCW + 3 * o + 1], vl);
      vl = fmaf(lp[60], sm[OFF_LOCW + 3 * o + 2], vl);
      vt = fmaf(tgt[(size_t)b * 30 + ti], sm[OFF_TGTW + o], vt);
    }
    sm[OFF_Pbuf + tid] = vp + pe;
    sm[OFF_Sbuf + tid] = vs + pe;
    sm[OFF_Abuf + tid] = va + pe;
    sm[OFF_Lbuf + tid] = vl + pe;
    sm[OFF_Tbuf + tid] = vt + pe;
  }
  __syncthreads();

  // ---------- phase A: ALL 8 K/V sets projected once ----------
  kvproj<30>(0, OFF_Ebuf, OFF_CINW, OFF_CINB, sm, tid);
  kvproj<32>(1, OFF_Pbuf, OFF_CINW, OFF_CINB, sm, tid);
  kvproj<32>(2, OFF_Sbuf, OFF_CINW, OFF_CINB, sm, tid);
  kvproj<32>(3, OFF_Abuf, OFF_CINW, OFF_CINB, sm, tid);
  kvproj<32>(4, OFF_Lbuf, OFF_CINW, OFF_CINB, sm, tid);
  kvproj<30>(5, OFF_Ebuf, OFF_SINW, OFF_SINB, sm, tid);
  kvproj<32>(6, OFF_Pbuf, OFF_SINW, OFF_SINB, sm, tid);
  kvproj<32>(7, OFF_Abuf, OFF_SINW, OFF_SINB, sm, tid);
  __syncthreads();

  // ---------- phase B: all 18 MHAs, straight-line, BARRIER-FREE ----------
  const int qi = tid >> 3, h = tid & 7;
  float carry;  // nrm(cross(s,l)) handed from s-target to a-target (same (qi,h) map)
  {
    // --- target e (rows 0..29) ---
    if (qi < 30) {
      const float* xr = sm + OFF_Ebuf + qi * 8;
      float qc = dot8(xr, sm + OFF_CINW + h * 8, sm[OFF_CINB + h]);
      float qs = dot8(xr, sm + OFF_SINW + h * 8, sm[OFF_SINB + h]);
      float cat = attn_nv<32>(qc, qi, h, 1, OFF_COUTW, OFF_COUTB, sm)   // cross(e,p)
                + attn_nv<32>(qc, qi, h, 3, OFF_COUTW, OFF_COUTB, sm)   // cross(e,a)
                + attn_nv<32>(qc, qi, h, 4, OFF_COUTW, OFF_COUTB, sm)   // cross(e,l)
                + attn_nv<30>(qs, qi, h, 5, OFF_SOUTW, OFF_SOUTB, sm)   // selfa(e)
                + attn_nv<32>(qc, qi, h, 2, OFF_COUTW, OFF_COUTB, sm);  // cross(e,s)
      sm[OFF_CAT + qi * 8 + h] = cat;
    }
    // --- target p (rows 30..61) ---
    {
      const float* xr = sm + OFF_Pbuf + qi * 8;
      float qc = dot8(xr, sm + OFF_CINW + h * 8, sm[OFF_CINB + h]);
      float qs = dot8(xr, sm + OFF_SINW + h * 8, sm[OFF_SINB + h]);
      float cat = attn_nv<30>(qc, qi, h, 0, OFF_COUTW, OFF_COUTB, sm)   // cross(p,e)
                + attn_nv<32>(qc, qi, h, 3, OFF_COUTW, OFF_COUTB, sm)   // cross(p,a)
                + attn_nv<32>(qc, qi, h, 4, OFF_COUTW, OFF_COUTB, sm)   // cross(p,l)
                + attn_nv<32>(qs, qi, h, 6, OFF_SOUTW, OFF_SOUTB, sm)   // selfa(p)
                + attn_nv<32>(qc, qi, h, 2, OFF_COUTW, OFF_COUTB, sm);  // cross(p,s)
      sm[OFF_CAT + (30 + qi) * 8 + h] = cat;
    }
    // --- target s (rows 94..125) ---
    {
      const float* xr = sm + OFF_Sbuf + qi * 8;
      float qc = dot8(xr, sm + OFF_CINW + h * 8, sm[OFF_CINB + h]);
      float n1 = attn_nv<30>(qc, qi, h, 0, OFF_COUTW, OFF_COUTB, sm);   // cross(s,e)
      float n2 = attn_nv<32>(qc, qi, h, 1, OFF_COUTW, OFF_COUTB, sm);   // cross(s,p)
      float n3 = attn_nv<32>(qc, qi, h, 3, OFF_COUTW, OFF_COUTB, sm);   // cross(s,a)
      carry    = attn_nv<32>(qc, qi, h, 4, OFF_COUTW, OFF_COUTB, sm);   // cross(s,l)
      sm[OFF_CAT + (94 + qi) * 8 + h] = n1 + n2 + n3 + carry;
    }
    // --- target a (rows 62..93); reuses carry = nrm(cross(s,l)) (original bug) ---
    {
      const float* xr = sm + OFF_Abuf + qi * 8;
      float qc = dot8(xr, sm + OFF_CINW + h * 8, sm[OFF_CINB + h]);
      float qs = dot8(xr, sm + OFF_SINW + h * 8, sm[OFF_SINB + h]);
      float cat = attn_nv<30>(qc, qi, h, 0, OFF_COUTW, OFF_COUTB, sm)   // cross(a,e)
                + attn_nv<32>(qc, qi, h, 1, OFF_COUTW, OFF_COUTB, sm)   // cross(a,p)
                + carry
                + attn_nv<32>(qs, qi, h, 7, OFF_SOUTW, OFF_SOUTB, sm)   // selfa(a)
                + attn_nv<32>(qc, qi, h, 2, OFF_COUTW, OFF_COUTB, sm);  // cross(a,s)
      sm[OFF_CAT + (62 + qi) * 8 + h] = cat;
    }
  }
  __syncthreads();

  // ---------- final MHA: kv-proj of CAT (126 rows) into aliased KF/VF ----------
  for (int j = tid; j < 1008; j += NT) {
    int r = j >> 3, hh = j & 7;
    const float* x = sm + OFF_CAT + r * 8;
    float kk = dot8(x, sm + OFF_OINW + 64 + hh * 8, sm[OFF_OINB + 8 + hh]);
    float vv = dot8(x, sm + OFF_OINW + 128 + hh * 8, sm[OFF_OINB + 16 + hh]);
    sm[OFF_KF + hh * 132 + r] = kk;
    sm[OFF_VF + hh * 132 + r] = vv;
  }
  __syncthreads();

  // ---------- final attention (Lk=126, single pass) ----------
  {
    float qf = dot8(sm + OFF_Tbuf + qi * 8, sm + OFF_OINW + h * 8, sm[OFF_OINB + h]);
    const float* Kp = sm + OFF_KF + h * 132;
    const float* Vp = sm + OFF_VF + h * 132;
    v4f l4 = {0.f,0.f,0.f,0.f}, A4 = {0.f,0.f,0.f,0.f};
    #pragma unroll
    for (int t = 0; t < 31; t++) {
      v4f kk = *(const v4f*)(Kp + 4 * t);
      v4f vv = *(const v4f*)(Vp + 4 * t);
      v4f sc = kk * qf;
      v4f ee = { EXP2F(sc.x), EXP2F(sc.y), EXP2F(sc.z), EXP2F(sc.w) };
      l4 += ee; A4 += ee * vv;
    }
    {
      v2f kk = *(const v2f*)(Kp + 124);
      v2f vv = *(const v2f*)(Vp + 124);
      v2f sc = kk * qf;
      v2f ee = { EXP2F(sc.x), EXP2F(sc.y) };
      l4.xy = l4.xy + ee; A4.xy = A4.xy + ee * vv;
    }
    v2f lp = l4.xy + l4.zw, ap = A4.xy + A4.zw;
    float ov = (ap.x + ap.y) * __builtin_amdgcn_rcpf(lp.x + lp.y);
    sm[OFF_QP + qi * 20 + h] = ov;
    float a = dot8(sm + OFF_QP + qi * 20, sm + OFF_OOUTW + h * 8, sm[OFF_OOUTB + h]);
    sm[OFF_Tbuf + qi * 8 + h] = a;  // per-thread read-before-write; waves own disjoint rows
  }
  __syncthreads();

  // ---------- fc1 (2 threads per output) + channel softmax ----------
  if (tid < 180) {
    int j = tid >> 1, p = tid & 1;
    const v4f* w4 = (const v4f*)(fc1_w + j * 256);
    const v4f* o4 = (const v4f*)(sm + OFF_Tbuf);
    v4f acc4 = {0.f, 0.f, 0.f, 0.f};
    #pragma unroll 8
    for (int c = p; c < 64; c += 2) acc4 += o4[c] * w4[c];
    v2f a2 = acc4.xy + acc4.zw;
    float acc = a2.x + a2.y;
    acc += __shfl_xor(acc, 1);
    if (p == 0) sm[OFF_FCO + j] = acc + sm[OFF_FC1B + j];
  }
  __syncthreads();
  if (tid < 30) {
    float x0 = sm[OFF_FCO + 3 * tid], x1 = sm[OFF_FCO + 3 * tid + 1], x2 = sm[OFF_FCO + 3 * tid + 2];
    float m = fmaxf(x0, fmaxf(x1, x2));
    float e0 = __expf(x0 - m), e1 = __expf(x1 - m), e2 = __expf(x2 - m);
    float inv = __builtin_amdgcn_rcpf(e0 + e1 + e2);
    float* op = out + (size_t)b * 90;
    op[tid]      = e0 * inv;
    op[30 + tid] = e1 * inv;
    op[60 + tid] = e2 * inv;
  }
#undef CP
#undef CPQ
}

extern "C" void kernel_launch(void* const* d_in, const int* in_sizes, int n_in,
                              void* d_out, int out_size, void* d_ws, size_t ws_size,
                              hipStream_t stream) {
  (void)n_in; (void)out_size; (void)d_ws; (void)ws_size;
  int B = in_sizes[0] / 4720;  // eeg = (B,2,20,118)
  cmt_kernel<<<B, NT, 0, stream>>>(
      (const float*)d_in[0],  (const float*)d_in[1],  (const float*)d_in[2],
      (const float*)d_in[3],  (const float*)d_in[4],  (const float*)d_in[5],
      (const float*)d_in[6],  (const float*)d_in[7],  (const float*)d_in[8],
      (const float*)d_in[9],  (const float*)d_in[10], (const float*)d_in[11],
      (const float*)d_in[12], (const float*)d_in[13], (const float*)d_in[14],
      (const float*)d_in[15], (const float*)d_in[16], (const float*)d_in[17],
      (const float*)d_in[18], (const float*)d_in[19], (const float*)d_in[20],
      (const float*)d_in[21], (const float*)d_in[22], (const float*)d_in[23],
      (const float*)d_in[24], (const float*)d_in[25], (const float*)d_in[26],
      (const float*)d_in[27], (const float*)d_in[28], (const float*)d_in[29],
      (float*)d_out);
}